// Round 1
// baseline (401.139 us; speedup 1.0000x reference)
//
#include <hip/hip_runtime.h>
#include <cstdint>
#include <cstddef>

typedef unsigned short u16;
typedef __attribute__((ext_vector_type(4))) float f32x4;
typedef __attribute__((ext_vector_type(8))) short bf16x8;

__device__ __forceinline__ u16 f2bf(float f) {
  unsigned int u = __builtin_bit_cast(unsigned int, f);
  u += 0x7fffu + ((u >> 16) & 1u);
  return (u16)(u >> 16);
}

// ---------------- weight transpose + fp32->bf16 ----------------
// src: [K][N] fp32 row-major  ->  dst: [N][K] bf16 row-major
__global__ __launch_bounds__(256) void transpose_w(const float* __restrict__ src,
                                                   u16* __restrict__ dst,
                                                   int K, int N) {
  __shared__ float tile[32][33];
  int n0 = blockIdx.x * 32, k0 = blockIdx.y * 32;
  int tx = threadIdx.x & 31, ty = threadIdx.x >> 5;  // 32 x 8
#pragma unroll
  for (int i = 0; i < 4; ++i)
    tile[ty + i * 8][tx] = src[(size_t)(k0 + ty + i * 8) * N + n0 + tx];
  __syncthreads();
#pragma unroll
  for (int i = 0; i < 4; ++i)
    dst[(size_t)(n0 + ty + i * 8) * K + k0 + tx] = f2bf(tile[tx][ty + i * 8]);
}

// ---------------- LayerNorm (row = 768 fp32) -> bf16 ----------------
__global__ __launch_bounds__(256) void ln_rows(const float* __restrict__ x,
                                               const float* __restrict__ g,
                                               const float* __restrict__ bb,
                                               u16* __restrict__ out) {
  int row = blockIdx.x;
  const float* xr = x + (size_t)row * 768;
  int t = threadIdx.x;
  float v0 = xr[t], v1 = xr[t + 256], v2 = xr[t + 512];
  float s = v0 + v1 + v2;
  float sq = v0 * v0 + v1 * v1 + v2 * v2;
#pragma unroll
  for (int o = 32; o > 0; o >>= 1) {
    s += __shfl_down(s, o);
    sq += __shfl_down(sq, o);
  }
  __shared__ float ss[4], s2[4];
  int w = t >> 6;
  if ((t & 63) == 0) { ss[w] = s; s2[w] = sq; }
  __syncthreads();
  s = ss[0] + ss[1] + ss[2] + ss[3];
  sq = s2[0] + s2[1] + s2[2] + s2[3];
  float mu = s * (1.f / 768.f);
  float var = sq * (1.f / 768.f) - mu * mu;
  float rs = rsqrtf(var + 1e-5f);
  u16* orow = out + (size_t)row * 768;
  orow[t]       = f2bf((v0 - mu) * rs * g[t]       + bb[t]);
  orow[t + 256] = f2bf((v1 - mu) * rs * g[t + 256] + bb[t + 256]);
  orow[t + 512] = f2bf((v2 - mu) * rs * g[t + 512] + bb[t + 512]);
}

// ---------------- bf16 MFMA GEMM: C = A[M,K] @ BT[N,K]^T ----------------
// EPI: 0 = store bf16; 1 = residual(fp32) add, store fp32; 2 = exact GELU, store bf16
template <int EPI>
__global__ __launch_bounds__(256, 2) void gemm_bt(const u16* __restrict__ A,
                                                  const u16* __restrict__ BT,
                                                  int M, int N, int K,
                                                  float* __restrict__ outF,
                                                  u16* __restrict__ outB,
                                                  const float* __restrict__ res) {
  __shared__ __align__(16) u16 Al[128 * 72];
  __shared__ __align__(16) u16 Bl[128 * 72];
  int tid = threadIdx.x;
  int lane = tid & 63, w = tid >> 6;
  int l16 = lane & 15, quad = lane >> 4;
  int wm = w >> 1, wn = w & 1;
  size_t rowA0 = (size_t)blockIdx.y * 128;
  size_t rowB0 = (size_t)blockIdx.x * 128;

  f32x4 acc[4][4] = {};

  for (int k0 = 0; k0 < K; k0 += 64) {
    __syncthreads();
#pragma unroll
    for (int i = 0; i < 4; ++i) {
      int chunk = tid + i * 256;           // 1024 chunks of 8 elems
      int r = chunk >> 3, c8 = chunk & 7;
      *(uint4*)&Al[r * 72 + c8 * 8] =
          *(const uint4*)&A[(rowA0 + r) * (size_t)K + k0 + c8 * 8];
      *(uint4*)&Bl[r * 72 + c8 * 8] =
          *(const uint4*)&BT[(rowB0 + r) * (size_t)K + k0 + c8 * 8];
    }
    __syncthreads();
#pragma unroll
    for (int ks = 0; ks < 2; ++ks) {
      bf16x8 af[4], bf[4];
#pragma unroll
      for (int mt = 0; mt < 4; ++mt)
        af[mt] = *(const bf16x8*)&Al[(wm * 64 + mt * 16 + l16) * 72 + ks * 32 + quad * 8];
#pragma unroll
      for (int nt = 0; nt < 4; ++nt)
        bf[nt] = *(const bf16x8*)&Bl[(wn * 64 + nt * 16 + l16) * 72 + ks * 32 + quad * 8];
#pragma unroll
      for (int mt = 0; mt < 4; ++mt)
#pragma unroll
        for (int nt = 0; nt < 4; ++nt)
          acc[mt][nt] = __builtin_amdgcn_mfma_f32_16x16x32_bf16(af[mt], bf[nt], acc[mt][nt], 0, 0, 0);
    }
  }

#pragma unroll
  for (int mt = 0; mt < 4; ++mt) {
#pragma unroll
    for (int i = 0; i < 4; ++i) {
      size_t row = rowA0 + wm * 64 + mt * 16 + quad * 4 + i;
#pragma unroll
      for (int nt = 0; nt < 4; ++nt) {
        size_t col = rowB0 + wn * 64 + nt * 16 + l16;
        float v = acc[mt][nt][i];
        if (EPI == 0) {
          outB[row * N + col] = f2bf(v);
        } else if (EPI == 1) {
          outF[row * N + col] = res[row * N + col] + v;
        } else {
          float ge = 0.5f * v * (1.f + erff(v * 0.70710678118654752f));
          outB[row * N + col] = f2bf(ge);
        }
      }
    }
  }
}

// ---------------- causal flash attention ----------------
// qkv: [B*T, 2304] bf16 (q | k | v, each 768 = 12 heads * 64)
// y:   [B*T, 768]  bf16
__global__ __launch_bounds__(256, 2) void flash_attn(const u16* __restrict__ qkv,
                                                     u16* __restrict__ y) {
  __shared__ __align__(16) u16 Kl[64 * 72];
  __shared__ __align__(16) u16 Vt[64 * 72];
  __shared__ __align__(16) u16 Pl[4][16 * 72];

  int tid = threadIdx.x;
  int lane = tid & 63, w = tid >> 6;
  int l16 = lane & 15, quad = lane >> 4;
  int qt = blockIdx.x, bh = blockIdx.y;
  int b = bh / 12, h = bh % 12;
  int q0 = qt * 64;
  int qw = q0 + w * 16;  // this wave's 16 q rows

  const u16* base = qkv + (size_t)b * 2048 * 2304;

  // Q fragments (A-operand layout): lane holds Q[qw + l16][quad*8 + j (+32)]
  bf16x8 qf[2];
  {
    const u16* qp = base + (size_t)(qw + l16) * 2304 + h * 64 + quad * 8;
    qf[0] = *(const bf16x8*)qp;
    qf[1] = *(const bf16x8*)(qp + 32);
  }

  f32x4 O[4] = {};
  float m_i[4], l_i[4];
#pragma unroll
  for (int i = 0; i < 4; ++i) { m_i[i] = -1e30f; l_i[i] = 0.f; }

  int ktiles = qt + 1;
  for (int kt = 0; kt < ktiles; ++kt) {
    int kt0 = kt * 64;
    __syncthreads();
    // stage K-tile [64 tok][64 d] and V-tile transposed [64 d][64 tok]
#pragma unroll
    for (int i = 0; i < 2; ++i) {
      int chunk = tid + i * 256;  // 512 chunks
      int r = chunk >> 3, c8 = chunk & 7;
      const u16* kp = base + (size_t)(kt0 + r) * 2304 + 768 + h * 64 + c8 * 8;
      *(uint4*)&Kl[r * 72 + c8 * 8] = *(const uint4*)kp;
      const u16* vp = base + (size_t)(kt0 + r) * 2304 + 1536 + h * 64 + c8 * 8;
      uint4 vv = *(const uint4*)vp;
      const u16* vs = (const u16*)&vv;
#pragma unroll
      for (int jj = 0; jj < 8; ++jj) {
        int j = (jj + lane) & 7;  // rotate to break bank conflicts
        Vt[(c8 * 8 + j) * 72 + r] = vs[j];
      }
    }
    __syncthreads();

    // S = Q @ K^T  (C-layout: row = quad*4+i, col = nt*16+l16)
    f32x4 S[4] = {};
#pragma unroll
    for (int nt = 0; nt < 4; ++nt) {
      bf16x8 b0 = *(const bf16x8*)&Kl[(nt * 16 + l16) * 72 + quad * 8];
      bf16x8 b1 = *(const bf16x8*)&Kl[(nt * 16 + l16) * 72 + 32 + quad * 8];
      S[nt] = __builtin_amdgcn_mfma_f32_16x16x32_bf16(qf[0], b0, S[nt], 0, 0, 0);
      S[nt] = __builtin_amdgcn_mfma_f32_16x16x32_bf16(qf[1], b1, S[nt], 0, 0, 0);
    }

    // scale + causal mask + online softmax
    float Sv[4][4], rowmax[4];
#pragma unroll
    for (int i = 0; i < 4; ++i) rowmax[i] = -1e30f;
#pragma unroll
    for (int nt = 0; nt < 4; ++nt) {
      int tk = kt0 + nt * 16 + l16;
#pragma unroll
      for (int i = 0; i < 4; ++i) {
        int tq = qw + quad * 4 + i;
        float v = S[nt][i] * 0.125f;
        if (tk > tq) v = -1e30f;
        Sv[nt][i] = v;
        rowmax[i] = fmaxf(rowmax[i], v);
      }
    }
#pragma unroll
    for (int i = 0; i < 4; ++i) {
#pragma unroll
      for (int o = 1; o < 16; o <<= 1) rowmax[i] = fmaxf(rowmax[i], __shfl_xor(rowmax[i], o));
    }
    float alpha[4], rowsum[4];
#pragma unroll
    for (int i = 0; i < 4; ++i) {
      float mn = fmaxf(m_i[i], rowmax[i]);
      alpha[i] = __expf(m_i[i] - mn);
      m_i[i] = mn;
      rowsum[i] = 0.f;
    }
#pragma unroll
    for (int nt = 0; nt < 4; ++nt) {
#pragma unroll
      for (int i = 0; i < 4; ++i) {
        float p = __expf(Sv[nt][i] - m_i[i]);
        rowsum[i] += p;
        Pl[w][(quad * 4 + i) * 72 + nt * 16 + l16] = f2bf(p);
      }
    }
#pragma unroll
    for (int i = 0; i < 4; ++i) {
#pragma unroll
      for (int o = 1; o < 16; o <<= 1) rowsum[i] += __shfl_xor(rowsum[i], o);
      l_i[i] = l_i[i] * alpha[i] + rowsum[i];
    }
#pragma unroll
    for (int dt = 0; dt < 4; ++dt)
#pragma unroll
      for (int i = 0; i < 4; ++i) O[dt][i] *= alpha[i];

    // wave-local P write -> read fence
    asm volatile("s_waitcnt lgkmcnt(0)" ::: "memory");

    // O += P @ V   (A = P [16 q][64 tok], B = Vt [d][tok])
#pragma unroll
    for (int c = 0; c < 2; ++c) {
      bf16x8 pf = *(const bf16x8*)&Pl[w][l16 * 72 + c * 32 + quad * 8];
#pragma unroll
      for (int dt = 0; dt < 4; ++dt) {
        bf16x8 vf = *(const bf16x8*)&Vt[(dt * 16 + l16) * 72 + c * 32 + quad * 8];
        O[dt] = __builtin_amdgcn_mfma_f32_16x16x32_bf16(pf, vf, O[dt], 0, 0, 0);
      }
    }
  }

  // epilogue: divide by l, store
#pragma unroll
  for (int dt = 0; dt < 4; ++dt) {
#pragma unroll
    for (int i = 0; i < 4; ++i) {
      int tq = qw + quad * 4 + i;
      float v = O[dt][i] / l_i[i];
      y[(size_t)(b * 2048 + tq) * 768 + h * 64 + dt * 16 + l16] = f2bf(v);
    }
  }
}

// ---------------- launch ----------------
extern "C" void kernel_launch(void* const* d_in, const int* in_sizes, int n_in,
                              void* d_out, int out_size, void* d_ws, size_t ws_size,
                              hipStream_t stream) {
  const float* x      = (const float*)d_in[0];
  const float* ln1_g  = (const float*)d_in[1];
  const float* ln1_b  = (const float*)d_in[2];
  const float* W_qkv  = (const float*)d_in[3];
  const float* W_attn = (const float*)d_in[4];
  const float* ln2_g  = (const float*)d_in[5];
  const float* ln2_b  = (const float*)d_in[6];
  const float* W_fc   = (const float*)d_in[7];
  const float* W_mlp  = (const float*)d_in[8];
  float* out = (float*)d_out;

  const int M = 4096;  // B*T
  char* p = (char*)d_ws;
  auto alloc = [&](size_t bytes) {
    char* r = p;
    p += (bytes + 255) & ~(size_t)255;
    return r;
  };
  u16* wt_qkv  = (u16*)alloc((size_t)2304 * 768 * 2);
  u16* wt_attn = (u16*)alloc((size_t)768 * 768 * 2);
  u16* wt_fc   = (u16*)alloc((size_t)3072 * 768 * 2);
  u16* wt_mlp  = (u16*)alloc((size_t)768 * 3072 * 2);
  u16* xn1     = (u16*)alloc((size_t)M * 768 * 2);
  u16* qkvb    = (u16*)alloc((size_t)M * 2304 * 2);
  u16* yb      = (u16*)alloc((size_t)M * 768 * 2);
  float* x1    = (float*)alloc((size_t)M * 768 * 4);
  u16* xn2     = (u16*)alloc((size_t)M * 768 * 2);
  u16* hb      = (u16*)alloc((size_t)M * 3072 * 2);

  // weight conversions (transposed bf16)
  transpose_w<<<dim3(2304 / 32, 768 / 32), 256, 0, stream>>>(W_qkv, wt_qkv, 768, 2304);
  transpose_w<<<dim3(768 / 32, 768 / 32), 256, 0, stream>>>(W_attn, wt_attn, 768, 768);
  transpose_w<<<dim3(3072 / 32, 768 / 32), 256, 0, stream>>>(W_fc, wt_fc, 768, 3072);
  transpose_w<<<dim3(768 / 32, 3072 / 32), 256, 0, stream>>>(W_mlp, wt_mlp, 3072, 768);

  // LN1
  ln_rows<<<M, 256, 0, stream>>>(x, ln1_g, ln1_b, xn1);
  // QKV = xn1 @ W_qkv  -> bf16
  gemm_bt<0><<<dim3(2304 / 128, M / 128), 256, 0, stream>>>(xn1, wt_qkv, M, 2304, 768,
                                                            nullptr, qkvb, nullptr);
  // attention
  flash_attn<<<dim3(32, 24), 256, 0, stream>>>(qkvb, yb);
  // x1 = x + y @ W_attn_proj  -> fp32
  gemm_bt<1><<<dim3(768 / 128, M / 128), 256, 0, stream>>>(yb, wt_attn, M, 768, 768,
                                                           x1, nullptr, x);
  // LN2
  ln_rows<<<M, 256, 0, stream>>>(x1, ln2_g, ln2_b, xn2);
  // h = gelu(xn2 @ W_fc) -> bf16
  gemm_bt<2><<<dim3(3072 / 128, M / 128), 256, 0, stream>>>(xn2, wt_fc, M, 3072, 768,
                                                            nullptr, hb, nullptr);
  // out = x1 + h @ W_mlp_proj -> fp32
  gemm_bt<1><<<dim3(768 / 128, M / 128), 256, 0, stream>>>(hb, wt_mlp, M, 768, 3072,
                                                           out, nullptr, x1);
}

// Round 2
// 320.958 us; speedup vs baseline: 1.2498x; 1.2498x over previous
//
#include <hip/hip_runtime.h>
#include <cstdint>
#include <cstddef>

typedef unsigned short u16;
typedef __attribute__((ext_vector_type(4))) float f32x4;
typedef __attribute__((ext_vector_type(8))) short bf16x8;

__device__ __forceinline__ u16 f2bf(float f) {
  unsigned int u = __builtin_bit_cast(unsigned int, f);
  u += 0x7fffu + ((u >> 16) & 1u);
  return (u16)(u >> 16);
}

// ---------------- weight transpose + fp32->bf16 ----------------
// src: [K][N] fp32 row-major  ->  dst: [N][K] bf16 row-major
__global__ __launch_bounds__(256) void transpose_w(const float* __restrict__ src,
                                                   u16* __restrict__ dst,
                                                   int K, int N) {
  __shared__ float tile[32][33];
  int n0 = blockIdx.x * 32, k0 = blockIdx.y * 32;
  int tx = threadIdx.x & 31, ty = threadIdx.x >> 5;  // 32 x 8
#pragma unroll
  for (int i = 0; i < 4; ++i)
    tile[ty + i * 8][tx] = src[(size_t)(k0 + ty + i * 8) * N + n0 + tx];
  __syncthreads();
#pragma unroll
  for (int i = 0; i < 4; ++i)
    dst[(size_t)(n0 + ty + i * 8) * K + k0 + tx] = f2bf(tile[tx][ty + i * 8]);
}

// ---------------- V transpose: qkvb [B*T][2304] -> vt [24][64][2048] ----------------
__global__ __launch_bounds__(256) void transpose_v(const u16* __restrict__ qkvb,
                                                   u16* __restrict__ vt) {
  __shared__ u16 tile[64 * 72];
  int t0 = blockIdx.x * 64;  // token tile within b
  int bh = blockIdx.y;       // 0..23
  int b = bh / 12, h = bh % 12;
  int tid = threadIdx.x;
  int c8 = tid & 7, r = tid >> 3;  // r 0..31
#pragma unroll
  for (int i = 0; i < 2; ++i) {
    int rr = r + i * 32;
    *(uint4*)&tile[rr * 72 + c8 * 8] =
        *(const uint4*)&qkvb[(size_t)(b * 2048 + t0 + rr) * 2304 + 1536 + h * 64 + c8 * 8];
  }
  __syncthreads();
#pragma unroll
  for (int i = 0; i < 2; ++i) {
    int dr = r + i * 32;
    u16 tmp[8];
#pragma unroll
    for (int j = 0; j < 8; ++j) tmp[j] = tile[(c8 * 8 + j) * 72 + dr];
    *(uint4*)&vt[((size_t)bh * 64 + dr) * 2048 + t0 + c8 * 8] = *(uint4*)tmp;
  }
}

__global__ void zero_counter(unsigned int* c) {
  if (threadIdx.x == 0) *c = 0u;
}

// ---------------- LayerNorm (row = 768 fp32) -> bf16 ----------------
__global__ __launch_bounds__(256) void ln_rows(const float* __restrict__ x,
                                               const float* __restrict__ g,
                                               const float* __restrict__ bb,
                                               u16* __restrict__ out) {
  int row = blockIdx.x;
  const float* xr = x + (size_t)row * 768;
  int t = threadIdx.x;
  float v0 = xr[t], v1 = xr[t + 256], v2 = xr[t + 512];
  float s = v0 + v1 + v2;
  float sq = v0 * v0 + v1 * v1 + v2 * v2;
#pragma unroll
  for (int o = 32; o > 0; o >>= 1) {
    s += __shfl_down(s, o);
    sq += __shfl_down(sq, o);
  }
  __shared__ float ss[4], s2[4];
  int w = t >> 6;
  if ((t & 63) == 0) { ss[w] = s; s2[w] = sq; }
  __syncthreads();
  s = ss[0] + ss[1] + ss[2] + ss[3];
  sq = s2[0] + s2[1] + s2[2] + s2[3];
  float mu = s * (1.f / 768.f);
  float var = sq * (1.f / 768.f) - mu * mu;
  float rs = rsqrtf(var + 1e-5f);
  u16* orow = out + (size_t)row * 768;
  orow[t]       = f2bf((v0 - mu) * rs * g[t]       + bb[t]);
  orow[t + 256] = f2bf((v1 - mu) * rs * g[t + 256] + bb[t + 256]);
  orow[t + 512] = f2bf((v2 - mu) * rs * g[t + 512] + bb[t + 512]);
}

// ---------------- bf16 MFMA GEMM: C = A[M,K] @ BT[N,K]^T ----------------
// EPI: 0 = store bf16; 1 = residual(fp32) add, store fp32; 2 = exact GELU, store bf16
template <int EPI>
__global__ __launch_bounds__(256, 2) void gemm_bt(const u16* __restrict__ A,
                                                  const u16* __restrict__ BT,
                                                  int M, int N, int K,
                                                  float* __restrict__ outF,
                                                  u16* __restrict__ outB,
                                                  const float* __restrict__ res) {
  __shared__ __align__(16) u16 Al[128 * 72];
  __shared__ __align__(16) u16 Bl[128 * 72];
  int tid = threadIdx.x;
  int lane = tid & 63, w = tid >> 6;
  int l16 = lane & 15, quad = lane >> 4;
  int wm = w >> 1, wn = w & 1;
  size_t rowA0 = (size_t)blockIdx.y * 128;
  size_t rowB0 = (size_t)blockIdx.x * 128;

  f32x4 acc[4][4] = {};

  for (int k0 = 0; k0 < K; k0 += 64) {
    __syncthreads();
#pragma unroll
    for (int i = 0; i < 4; ++i) {
      int chunk = tid + i * 256;           // 1024 chunks of 8 elems
      int r = chunk >> 3, c8 = chunk & 7;
      *(uint4*)&Al[r * 72 + c8 * 8] =
          *(const uint4*)&A[(rowA0 + r) * (size_t)K + k0 + c8 * 8];
      *(uint4*)&Bl[r * 72 + c8 * 8] =
          *(const uint4*)&BT[(rowB0 + r) * (size_t)K + k0 + c8 * 8];
    }
    __syncthreads();
#pragma unroll
    for (int ks = 0; ks < 2; ++ks) {
      bf16x8 af[4], bf[4];
#pragma unroll
      for (int mt = 0; mt < 4; ++mt)
        af[mt] = *(const bf16x8*)&Al[(wm * 64 + mt * 16 + l16) * 72 + ks * 32 + quad * 8];
#pragma unroll
      for (int nt = 0; nt < 4; ++nt)
        bf[nt] = *(const bf16x8*)&Bl[(wn * 64 + nt * 16 + l16) * 72 + ks * 32 + quad * 8];
#pragma unroll
      for (int mt = 0; mt < 4; ++mt)
#pragma unroll
        for (int nt = 0; nt < 4; ++nt)
          acc[mt][nt] = __builtin_amdgcn_mfma_f32_16x16x32_bf16(af[mt], bf[nt], acc[mt][nt], 0, 0, 0);
    }
  }

#pragma unroll
  for (int mt = 0; mt < 4; ++mt) {
#pragma unroll
    for (int i = 0; i < 4; ++i) {
      size_t row = rowA0 + wm * 64 + mt * 16 + quad * 4 + i;
#pragma unroll
      for (int nt = 0; nt < 4; ++nt) {
        size_t col = rowB0 + wn * 64 + nt * 16 + l16;
        float v = acc[mt][nt][i];
        if (EPI == 0) {
          outB[row * N + col] = f2bf(v);
        } else if (EPI == 1) {
          outF[row * N + col] = res[row * N + col] + v;
        } else {
          float ge = 0.5f * v * (1.f + erff(v * 0.70710678118654752f));
          outB[row * N + col] = f2bf(ge);
        }
      }
    }
  }
}

// ---------------- causal flash attention (work-queue, KB=128) ----------------
// qkv: [B*T, 2304] bf16 (q | k | v); vt: [24][64][2048] bf16; y: [B*T, 768] bf16
__global__ __launch_bounds__(256, 2) void flash_attn(const u16* __restrict__ qkv,
                                                     const u16* __restrict__ vt,
                                                     u16* __restrict__ y,
                                                     unsigned int* __restrict__ ctr) {
  __shared__ __align__(16) u16 Kl[128 * 72];
  __shared__ __align__(16) u16 Vl[64 * 136];
  __shared__ __align__(16) u16 Pl[4][16 * 136];
  __shared__ unsigned int s_unit;

  int tid = threadIdx.x;
  int lane = tid & 63, w = tid >> 6;
  int l16 = lane & 15, quad = lane >> 4;

  for (;;) {
    __syncthreads();  // protect s_unit + LDS reuse across units
    if (tid == 0) s_unit = atomicAdd(ctr, 1u);
    __syncthreads();
    unsigned int u = s_unit;
    if (u >= 768u) return;

    int qt = 31 - (int)(u / 24u);  // heavy units first (LPT)
    int bh = (int)(u % 24u);
    int b = bh / 12, h = bh % 12;
    int q0 = qt * 64;
    int qw = q0 + w * 16;

    const u16* base = qkv + (size_t)b * 2048 * 2304;

    bf16x8 qf[2];
    {
      const u16* qp = base + (size_t)(qw + l16) * 2304 + h * 64 + quad * 8;
      qf[0] = *(const bf16x8*)qp;
      qf[1] = *(const bf16x8*)(qp + 32);
    }

    f32x4 O[4] = {};
    float m_i[4], l_i[4];
#pragma unroll
    for (int i = 0; i < 4; ++i) { m_i[i] = -1e30f; l_i[i] = 0.f; }

    int nkb = qt / 2 + 1;
    for (int kb = 0; kb < nkb; ++kb) {
      int kt0 = kb * 128;
      __syncthreads();
      // stage K [128 tok][64 d]
#pragma unroll
      for (int i = 0; i < 4; ++i) {
        int chunk = tid + i * 256;
        int r = chunk >> 3, c8 = chunk & 7;
        *(uint4*)&Kl[r * 72 + c8 * 8] =
            *(const uint4*)&base[(size_t)(kt0 + r) * 2304 + 768 + h * 64 + c8 * 8];
      }
      // stage Vt [64 d][128 tok]
#pragma unroll
      for (int i = 0; i < 4; ++i) {
        int chunk = tid + i * 256;
        int r = chunk >> 4, c16 = chunk & 15;
        *(uint4*)&Vl[r * 136 + c16 * 8] =
            *(const uint4*)&vt[((size_t)bh * 64 + r) * 2048 + kt0 + c16 * 8];
      }
      __syncthreads();

      // S = Q @ K^T : 16x128 per wave
      f32x4 S[8];
#pragma unroll
      for (int nt = 0; nt < 8; ++nt) {
        f32x4 z = {};
        bf16x8 b0 = *(const bf16x8*)&Kl[(nt * 16 + l16) * 72 + quad * 8];
        bf16x8 b1 = *(const bf16x8*)&Kl[(nt * 16 + l16) * 72 + 32 + quad * 8];
        z = __builtin_amdgcn_mfma_f32_16x16x32_bf16(qf[0], b0, z, 0, 0, 0);
        S[nt] = __builtin_amdgcn_mfma_f32_16x16x32_bf16(qf[1], b1, z, 0, 0, 0);
      }

      const float sc = 0.125f * 1.44269504088896340736f;  // scale * log2(e)
      float rowmax[4];
#pragma unroll
      for (int i = 0; i < 4; ++i) rowmax[i] = -1e30f;
      if (kb == nkb - 1) {  // diagonal block: mask
#pragma unroll
        for (int nt = 0; nt < 8; ++nt) {
          int tk = kt0 + nt * 16 + l16;
#pragma unroll
          for (int i = 0; i < 4; ++i) {
            int tq = qw + quad * 4 + i;
            float v = S[nt][i] * sc;
            if (tk > tq) v = -1e30f;
            S[nt][i] = v;
            rowmax[i] = fmaxf(rowmax[i], v);
          }
        }
      } else {
#pragma unroll
        for (int nt = 0; nt < 8; ++nt)
#pragma unroll
          for (int i = 0; i < 4; ++i) {
            float v = S[nt][i] * sc;
            S[nt][i] = v;
            rowmax[i] = fmaxf(rowmax[i], v);
          }
      }
#pragma unroll
      for (int i = 0; i < 4; ++i) {
#pragma unroll
        for (int o = 1; o < 16; o <<= 1) rowmax[i] = fmaxf(rowmax[i], __shfl_xor(rowmax[i], o));
      }
      float alpha[4];
#pragma unroll
      for (int i = 0; i < 4; ++i) {
        float mn = fmaxf(m_i[i], rowmax[i]);
        alpha[i] = exp2f(m_i[i] - mn);
        m_i[i] = mn;
      }
      float rowsum[4] = {0.f, 0.f, 0.f, 0.f};
#pragma unroll
      for (int nt = 0; nt < 8; ++nt)
#pragma unroll
        for (int i = 0; i < 4; ++i) {
          float p = exp2f(S[nt][i] - m_i[i]);
          rowsum[i] += p;
          Pl[w][(quad * 4 + i) * 136 + nt * 16 + l16] = f2bf(p);
        }
#pragma unroll
      for (int i = 0; i < 4; ++i) {
#pragma unroll
        for (int o = 1; o < 16; o <<= 1) rowsum[i] += __shfl_xor(rowsum[i], o);
        l_i[i] = l_i[i] * alpha[i] + rowsum[i];
      }
#pragma unroll
      for (int dt = 0; dt < 4; ++dt)
#pragma unroll
        for (int i = 0; i < 4; ++i) O[dt][i] *= alpha[i];

      asm volatile("s_waitcnt lgkmcnt(0)" ::: "memory");  // wave-local P visible

      // O += P @ V  (A = P[16 q][128 tok], B = Vt[d][tok])
#pragma unroll
      for (int c = 0; c < 4; ++c) {
        bf16x8 pf = *(const bf16x8*)&Pl[w][l16 * 136 + c * 32 + quad * 8];
#pragma unroll
        for (int dt = 0; dt < 4; ++dt) {
          bf16x8 vf = *(const bf16x8*)&Vl[(dt * 16 + l16) * 136 + c * 32 + quad * 8];
          O[dt] = __builtin_amdgcn_mfma_f32_16x16x32_bf16(pf, vf, O[dt], 0, 0, 0);
        }
      }
    }

    // epilogue: divide by l, store
#pragma unroll
    for (int dt = 0; dt < 4; ++dt) {
#pragma unroll
      for (int i = 0; i < 4; ++i) {
        int tq = qw + quad * 4 + i;
        float v = O[dt][i] / l_i[i];
        y[(size_t)(b * 2048 + tq) * 768 + h * 64 + dt * 16 + l16] = f2bf(v);
      }
    }
  }
}

// ---------------- launch ----------------
extern "C" void kernel_launch(void* const* d_in, const int* in_sizes, int n_in,
                              void* d_out, int out_size, void* d_ws, size_t ws_size,
                              hipStream_t stream) {
  const float* x      = (const float*)d_in[0];
  const float* ln1_g  = (const float*)d_in[1];
  const float* ln1_b  = (const float*)d_in[2];
  const float* W_qkv  = (const float*)d_in[3];
  const float* W_attn = (const float*)d_in[4];
  const float* ln2_g  = (const float*)d_in[5];
  const float* ln2_b  = (const float*)d_in[6];
  const float* W_fc   = (const float*)d_in[7];
  const float* W_mlp  = (const float*)d_in[8];
  float* out = (float*)d_out;

  const int M = 4096;  // B*T
  char* p = (char*)d_ws;
  auto alloc = [&](size_t bytes) {
    char* r = p;
    p += (bytes + 255) & ~(size_t)255;
    return r;
  };
  u16* wt_qkv  = (u16*)alloc((size_t)2304 * 768 * 2);
  u16* wt_attn = (u16*)alloc((size_t)768 * 768 * 2);
  u16* wt_fc   = (u16*)alloc((size_t)3072 * 768 * 2);
  u16* wt_mlp  = (u16*)alloc((size_t)768 * 3072 * 2);
  u16* xn1     = (u16*)alloc((size_t)M * 768 * 2);
  u16* qkvb    = (u16*)alloc((size_t)M * 2304 * 2);
  u16* yb      = (u16*)alloc((size_t)M * 768 * 2);
  float* x1    = (float*)alloc((size_t)M * 768 * 4);
  u16* xn2     = (u16*)alloc((size_t)M * 768 * 2);
  u16* hb      = (u16*)alloc((size_t)M * 3072 * 2);
  u16* vt      = (u16*)alloc((size_t)24 * 64 * 2048 * 2);
  unsigned int* ctr = (unsigned int*)alloc(256);

  // weight conversions (transposed bf16)
  transpose_w<<<dim3(2304 / 32, 768 / 32), 256, 0, stream>>>(W_qkv, wt_qkv, 768, 2304);
  transpose_w<<<dim3(768 / 32, 768 / 32), 256, 0, stream>>>(W_attn, wt_attn, 768, 768);
  transpose_w<<<dim3(3072 / 32, 768 / 32), 256, 0, stream>>>(W_fc, wt_fc, 768, 3072);
  transpose_w<<<dim3(768 / 32, 3072 / 32), 256, 0, stream>>>(W_mlp, wt_mlp, 3072, 768);

  // LN1
  ln_rows<<<M, 256, 0, stream>>>(x, ln1_g, ln1_b, xn1);
  // QKV = xn1 @ W_qkv  -> bf16
  gemm_bt<0><<<dim3(2304 / 128, M / 128), 256, 0, stream>>>(xn1, wt_qkv, M, 2304, 768,
                                                            nullptr, qkvb, nullptr);
  // V transpose for attention + queue reset
  transpose_v<<<dim3(32, 24), 256, 0, stream>>>(qkvb, vt);
  zero_counter<<<1, 64, 0, stream>>>(ctr);
  // attention
  flash_attn<<<768, 256, 0, stream>>>(qkvb, vt, yb, ctr);
  // x1 = x + y @ W_attn_proj  -> fp32
  gemm_bt<1><<<dim3(768 / 128, M / 128), 256, 0, stream>>>(yb, wt_attn, M, 768, 768,
                                                           x1, nullptr, x);
  // LN2
  ln_rows<<<M, 256, 0, stream>>>(x1, ln2_g, ln2_b, xn2);
  // h = gelu(xn2 @ W_fc) -> bf16
  gemm_bt<2><<<dim3(3072 / 128, M / 128), 256, 0, stream>>>(xn2, wt_fc, M, 3072, 768,
                                                            nullptr, hb, nullptr);
  // out = x1 + h @ W_mlp_proj -> fp32
  gemm_bt<1><<<dim3(768 / 128, M / 128), 256, 0, stream>>>(hb, wt_mlp, M, 768, 3072,
                                                           out, nullptr, x1);
}